// Round 7
// baseline (102.775 us; speedup 1.0000x reference)
//
#include <hip/hip_runtime.h>
#include <hip/hip_bf16.h>

#define NROWS 4096
#define TWO_N 8192
#define DDIM 64
#define INV_T 20.0f
// exp(dot*INV_T) = 2^(dot*INV_T*log2e); fold sqrt of that scale into each operand
#define SCALE2 5.3716292f   // sqrt(20 * 1.4426950408889634)

typedef short bf16x8 __attribute__((ext_vector_type(8)));
typedef float f32x4 __attribute__((ext_vector_type(4)));

__device__ __forceinline__ unsigned short f32_to_bf16_rne(float f) {
    unsigned int u = __float_as_uint(f);
    return (unsigned short)((u + 0x7fffu + ((u >> 16) & 1u)) >> 16);
}

__device__ __forceinline__ float fast_exp2(float x) {
    float r;
    asm("v_exp_f32 %0, %1" : "=v"(r) : "v"(x));
    return r;
}

// featsT fragment-major layout: element (row=16g+lr, col=kb*32+lk*8+e) at
//   featsT[g*1024 + kb*512 + (lk*16+lr)*8 + e]
// -> an MFMA fragment load is featsT + g*1024 + kb*512 + lane*8 (1KB coalesced).

// ---- kernel 1: convert f32 -> scaled bf16 fragment-major + posdot + zero Ng/out ----
__global__ void prep_kernel(const float* __restrict__ f1,
                            const float* __restrict__ f2,
                            unsigned short* __restrict__ featsT,
                            float* __restrict__ posdot,
                            float* __restrict__ Ng,
                            float* __restrict__ out) {
    if (blockIdx.x < 8) {
        float4 z = make_float4(0.f, 0.f, 0.f, 0.f);
        reinterpret_cast<float4*>(Ng)[blockIdx.x * 256 + threadIdx.x] = z;
        if (blockIdx.x == 0 && threadIdx.x == 0) out[0] = 0.f;
    }
    int t = blockIdx.x * blockDim.x + threadIdx.x;
    int r = t >> 4;
    int q = t & 15;
    int j = r * DDIM + q * 4;
    float4 a = *reinterpret_cast<const float4*>(&f1[j]);
    float4 b = *reinterpret_cast<const float4*>(&f2[j]);
    // posdot from unscaled values (natural-log exponent, f32-exact path)
    float d = a.x * b.x + a.y * b.y + a.z * b.z + a.w * b.w;
    d += __shfl_xor(d, 1);
    d += __shfl_xor(d, 2);
    d += __shfl_xor(d, 4);
    d += __shfl_xor(d, 8);
    if (q == 0) posdot[r] = d * INV_T;
    // scaled bf16 store, fragment-major
    ushort4 ua = make_ushort4(f32_to_bf16_rne(a.x * SCALE2), f32_to_bf16_rne(a.y * SCALE2),
                              f32_to_bf16_rne(a.z * SCALE2), f32_to_bf16_rne(a.w * SCALE2));
    ushort4 ub = make_ushort4(f32_to_bf16_rne(b.x * SCALE2), f32_to_bf16_rne(b.y * SCALE2),
                              f32_to_bf16_rne(b.z * SCALE2), f32_to_bf16_rne(b.w * SCALE2));
    int g1 = r >> 4;
    int lr = r & 15;
    int kb = q >> 3;
    int lk = (q & 7) >> 1;
    int e  = (q & 1) * 4;
    int off = g1 * 1024 + kb * 512 + (lk * 16 + lr) * 8 + e;
    *reinterpret_cast<ushort4*>(&featsT[off]) = ua;                 // f1: groups 0..255
    *reinterpret_cast<ushort4*>(&featsT[off + 256 * 1024]) = ub;    // f2: groups 256..511
}

// ---- kernel 2: symmetric Ng accumulation over upper-triangle 128x128 tiles ----
// 8 waves (4M x 2N), each wave one 32x64 sub-tile. Strict-upper tiles add row
// sums to Ng[rows] AND col sums to Ng[cols]; diagonal tiles row sums only.
__global__ __launch_bounds__(512, 4) void ng_kernel(const unsigned short* __restrict__ featsT,
                                                    const int* __restrict__ label,
                                                    float* __restrict__ Ng) {
    const int pr = blockIdx.y;       // row panel
    const int pc = blockIdx.x;       // col panel
    if (pc < pr) return;
    const bool diag = (pc == pr);

    const int tid = threadIdx.x;
    const int wid = tid >> 6;
    const int lane = tid & 63;
    const int lr = lane & 15;
    const int lk = lane >> 4;
    const int wm = wid >> 1;         // 0..3
    const int wn = wid & 1;          // 0..1

    const int rowBase = pr * 128 + wm * 32;
    const int colBase = pc * 128 + wn * 64;
    const int gr0 = rowBase >> 4;
    const int gc0 = colBase >> 4;

    f32x4 acc[2][4];
    f32x4 zero = {0.f, 0.f, 0.f, 0.f};
    #pragma unroll
    for (int m = 0; m < 2; ++m)
        #pragma unroll
        for (int n = 0; n < 4; ++n) acc[m][n] = zero;

    #pragma unroll
    for (int kb = 0; kb < 2; ++kb) {
        bf16x8 afr[2], bfr[4];
        #pragma unroll
        for (int m = 0; m < 2; ++m)
            afr[m] = *reinterpret_cast<const bf16x8*>(
                &featsT[(gr0 + m) * 1024 + kb * 512 + lane * 8]);
        #pragma unroll
        for (int n = 0; n < 4; ++n)
            bfr[n] = *reinterpret_cast<const bf16x8*>(
                &featsT[(gc0 + n) * 1024 + kb * 512 + lane * 8]);
        #pragma unroll
        for (int m = 0; m < 2; ++m)
            #pragma unroll
            for (int n = 0; n < 4; ++n)
                acc[m][n] = __builtin_amdgcn_mfma_f32_16x16x32_bf16(afr[m], bfr[n], acc[m][n], 0, 0, 0);
    }

    // labels straight from global (L1-hot, few cache lines)
    int rl[2][4];
    #pragma unroll
    for (int m = 0; m < 2; ++m)
        #pragma unroll
        for (int r = 0; r < 4; ++r)
            rl[m][r] = label[(rowBase + m * 16 + lk * 4 + r) & (NROWS - 1)];
    int cl[4];
    #pragma unroll
    for (int n = 0; n < 4; ++n)
        cl[n] = label[(colBase + n * 16 + lr) & (NROWS - 1)];

    float rsum[2][4];
    float csum[4] = {0.f, 0.f, 0.f, 0.f};
    #pragma unroll
    for (int m = 0; m < 2; ++m)
        #pragma unroll
        for (int r = 0; r < 4; ++r) {
            int lab = rl[m][r];
            float s = 0.f;
            #pragma unroll
            for (int n = 0; n < 4; ++n) {
                float e = fast_exp2(acc[m][n][r]);   // 2^(dot*INV_T*log2e) = exp(dot/T)
                float me = (cl[n] != lab) ? e : 0.f;
                s += me;
                csum[n] += me;
            }
            rsum[m][r] = s;
        }

    // row sums: reduce across the 16 lr lanes
    #pragma unroll
    for (int m = 0; m < 2; ++m)
        #pragma unroll
        for (int r = 0; r < 4; ++r) {
            float v = rsum[m][r];
            v += __shfl_xor(v, 1);
            v += __shfl_xor(v, 2);
            v += __shfl_xor(v, 4);
            v += __shfl_xor(v, 8);
            if (lr == 0)
                atomicAdd(&Ng[rowBase + m * 16 + lk * 4 + r], v);
        }

    // col sums (transpose contribution): reduce across the 4 lk groups
    if (!diag) {
        #pragma unroll
        for (int n = 0; n < 4; ++n) {
            float v = csum[n];
            v += __shfl_xor(v, 16);
            v += __shfl_xor(v, 32);
            if (lane < 16)
                atomicAdd(&Ng[colBase + n * 16 + lr], v);
        }
    }
}

// ---- kernel 3: final loss (16 blocks x 256 threads, atomic partial sums) ----
__global__ void final_kernel(const float* __restrict__ Ng,
                             const float* __restrict__ posdot,
                             const int* __restrict__ label,
                             float* __restrict__ out) {
    __shared__ int cnt[16];
    __shared__ float red[4];
    int tid = threadIdx.x;
    if (tid < 16) cnt[tid] = 0;
    __syncthreads();
    for (int i = tid; i < NROWS; i += 256) atomicAdd(&cnt[label[i]], 1);
    __syncthreads();
    float s = 0.f;
    #pragma unroll
    for (int k = 0; k < 2; ++k) {
        int i = blockIdx.x * 512 + k * 256 + tid;
        int base = i & (NROWS - 1);
        float pd = posdot[base];
        float gs = 2.0f * (float)cnt[label[base]];
        s += (__logf(Ng[i] + __expf(pd)) - pd) / gs;
    }
    #pragma unroll
    for (int m = 32; m; m >>= 1) s += __shfl_xor(s, m);
    if ((tid & 63) == 0) red[tid >> 6] = s;
    __syncthreads();
    if (tid == 0) atomicAdd(out, red[0] + red[1] + red[2] + red[3]);
}

extern "C" void kernel_launch(void* const* d_in, const int* in_sizes, int n_in,
                              void* d_out, int out_size, void* d_ws, size_t ws_size,
                              hipStream_t stream) {
    const float* f1 = (const float*)d_in[0];
    const float* f2 = (const float*)d_in[1];
    const int* label = (const int*)d_in[2];
    float* out = (float*)d_out;

    char* ws = (char*)d_ws;
    unsigned short* featsT = (unsigned short*)ws;                 // 1 MB
    float* Ng     = (float*)(ws + (size_t)TWO_N * DDIM * 2);      // 32 KB
    float* posdot = (float*)(ws + (size_t)TWO_N * DDIM * 2 + TWO_N * 4);  // 16 KB

    prep_kernel<<<dim3(NROWS * DDIM / 4 / 256), dim3(256), 0, stream>>>(f1, f2, featsT, posdot, Ng, out);
    ng_kernel<<<dim3(TWO_N / 128, TWO_N / 128), dim3(512), 0, stream>>>(featsT, label, Ng);
    final_kernel<<<dim3(TWO_N / 512), dim3(256), 0, stream>>>(Ng, posdot, label, out);
}